// Round 12
// baseline (202.864 us; speedup 1.0000x reference)
//
#include <hip/hip_runtime.h>
#include <math.h>

#define THREADS 256
#define CHUNKS 512          // stage-1 row chunks -> 4*512 = 2048 blocks (8/CU)

typedef int v4i __attribute__((ext_vector_type(4)));

__device__ __forceinline__ float4 ntload4(const float* p) {
    v4i t = __builtin_nontemporal_load(reinterpret_cast<const v4i*>(p));
    float4 r;
    r.x = __int_as_float(t.x); r.y = __int_as_float(t.y);
    r.z = __int_as_float(t.z); r.w = __int_as_float(t.w);
    return r;
}
__device__ __forceinline__ void ntstore4(float* p, const float4 v) {
    v4i t;
    t.x = __float_as_int(v.x); t.y = __float_as_int(v.y);
    t.z = __float_as_int(v.z); t.w = __float_as_int(v.w);
    __builtin_nontemporal_store(t, reinterpret_cast<v4i*>(p));
}

// gelu_tanh(m) = 0.5*m*(1+tanh(inner)) = m * sigmoid(2*inner)
__device__ __forceinline__ float gelu_fast(float m) {
    const float inner = 0.7978845608028654f * (m + 0.044715f * m * m * m);
    return m / (1.0f + __expf(-2.0f * inner));
}

// ---------------- Kernel 1: column partial sums of W (deterministic) -------
// W nt-loaded: streamed once, must not evict x from L3.
__global__ __launch_bounds__(THREADS)
void colsum_partials_kernel(const float* __restrict__ W, float* __restrict__ partials,
                            int O, int N, int rows_per_chunk) {
    int col = (blockIdx.x * THREADS + threadIdx.x) * 4;
    if (col >= N) return;
    int r0 = blockIdx.y * rows_per_chunk;
    int r1 = r0 + rows_per_chunk; if (r1 > O) r1 = O;
    float ax = 0.f, ay = 0.f, az = 0.f, aw = 0.f;
    #pragma unroll 4
    for (int r = r0; r < r1; ++r) {
        const float4 v = ntload4(W + (size_t)r * N + col);
        ax += v.x; ay += v.y; az += v.z; aw += v.w;
    }
    *reinterpret_cast<float4*>(partials + (size_t)blockIdx.y * N + col) =
        make_float4(ax, ay, az, aw);
}

// ------ Kernel 2: PARALLEL reduce partials -> c (1024 blocks) + bias sum ----
__global__ __launch_bounds__(THREADS)
void reduce_par_kernel(const float* __restrict__ partials,
                       const float* __restrict__ bias, const float* __restrict__ sub,
                       float* __restrict__ c, float* __restrict__ cb,
                       int N, int O, int chunks) {
    const int ncolg = N >> 2;
    const int t = threadIdx.x;
    if ((int)blockIdx.x == ncolg) {          // bias block
        float s = 0.f;
        for (int i = t; i < O; i += THREADS) s += bias[i] - sub[i];
        #pragma unroll
        for (int off = 32; off > 0; off >>= 1) s += __shfl_down(s, off, 64);
        __shared__ float lds[THREADS / 64];
        if ((t & 63) == 0) lds[t >> 6] = s;
        __syncthreads();
        if (t == 0) {
            float tt = 0.f;
            #pragma unroll
            for (int w = 0; w < THREADS / 64; ++w) tt += lds[w];
            *cb = tt;
        }
        return;
    }
    const int colg = blockIdx.x << 2;
    float ax = 0.f, ay = 0.f, az = 0.f, aw = 0.f;
    for (int k = t; k < chunks; k += THREADS) {
        const float4 v = *reinterpret_cast<const float4*>(partials + (size_t)k * N + colg);
        ax += v.x; ay += v.y; az += v.z; aw += v.w;
    }
    #pragma unroll
    for (int off = 32; off > 0; off >>= 1) {
        ax += __shfl_down(ax, off, 64);
        ay += __shfl_down(ay, off, 64);
        az += __shfl_down(az, off, 64);
        aw += __shfl_down(aw, off, 64);
    }
    __shared__ float4 lds4[THREADS / 64];
    if ((t & 63) == 0) lds4[t >> 6] = make_float4(ax, ay, az, aw);
    __syncthreads();
    if (t == 0) {
        float4 r = lds4[0];
        #pragma unroll
        for (int w = 1; w < THREADS / 64; ++w) {
            r.x += lds4[w].x; r.y += lds4[w].y; r.z += lds4[w].z; r.w += lds4[w].w;
        }
        *reinterpret_cast<float4*>(c + colg) = r;
    }
}

// ---- Kernel 3a: row sums -> g[M] (pure read; REGULAR x loads warm L3) ------
template<int VPL>
__global__ __launch_bounds__(THREADS)
void rowsum_gelu_kernel(const float* __restrict__ x, const float* __restrict__ c,
                        const float* __restrict__ cb, const int* __restrict__ of_ptr,
                        float* __restrict__ g, int M, int N) {
    const int wave = threadIdx.x >> 6;
    const int lane = threadIdx.x & 63;
    const int row = blockIdx.x * (THREADS / 64) + wave;
    if (row >= M) return;
    const size_t base = (size_t)row * N;

    float partial = 0.f;
    #pragma unroll
    for (int k = 0; k < VPL; ++k) {
        const int idx = (k * 64 + lane) * 4;
        const float4 xx = *reinterpret_cast<const float4*>(x + base + idx);  // allocate L3
        const float4 cc = *reinterpret_cast<const float4*>(c + idx);          // L1-hot
        partial += xx.x * cc.x + xx.y * cc.y + xx.z * cc.z + xx.w * cc.w;
    }
    #pragma unroll
    for (int off = 1; off < 64; off <<= 1) partial += __shfl_xor(partial, off, 64);
    if (lane == 0) g[row] = gelu_fast((partial + *cb) / (float)(*of_ptr));
}

// ---- Kernel 3b: out = x + g[row]  (m13-shaped copy; REVERSE traversal) -----
// Reverse order reads the most-recently-cached x lines first; nt-store out
// so the write stream neither RFOs nor evicts x from L3.
__global__ __launch_bounds__(THREADS)
void addg_kernel(const float* __restrict__ x, const float* __restrict__ g,
                 float* __restrict__ out, long long n4, int shift) {
    const long long stride = (long long)gridDim.x * THREADS;
    for (long long i = (long long)blockIdx.x * THREADS + threadIdx.x; i < n4; i += stride) {
        const long long j = n4 - 1 - i;                    // reverse
        const float4 xx = *reinterpret_cast<const float4*>(x + 4 * j);
        const float gg = g[j >> shift];                    // wave-uniform, L1 broadcast
        ntstore4(out + 4 * j, make_float4(xx.x + gg, xx.y + gg, xx.z + gg, xx.w + gg));
    }
}

// ---- single-pass row kernel (other N) and generic fallback ------------------
template<int VPL>
__global__ __launch_bounds__(THREADS)
void row_wave_kernel(const float* __restrict__ x, const float* __restrict__ c,
                     const float* __restrict__ cb, const int* __restrict__ of_ptr,
                     float* __restrict__ out, int M, int N) {
    const int wave = threadIdx.x >> 6;
    const int lane = threadIdx.x & 63;
    const int row = blockIdx.x * (THREADS / 64) + wave;
    if (row >= M) return;
    const size_t base = (size_t)row * N;
    float4 xv[VPL];
    float partial = 0.f;
    #pragma unroll
    for (int k = 0; k < VPL; ++k) {
        const int idx = (k * 64 + lane) * 4;
        const float4 xx = ntload4(x + base + idx);
        const float4 cc = *reinterpret_cast<const float4*>(c + idx);
        xv[k] = xx;
        partial += xx.x * cc.x + xx.y * cc.y + xx.z * cc.z + xx.w * cc.w;
    }
    #pragma unroll
    for (int off = 1; off < 64; off <<= 1) partial += __shfl_xor(partial, off, 64);
    const float g = gelu_fast((partial + *cb) / (float)(*of_ptr));
    #pragma unroll
    for (int k = 0; k < VPL; ++k) {
        const int idx = (k * 64 + lane) * 4;
        const float4 xx = xv[k];
        *reinterpret_cast<float4*>(out + base + idx) =
            make_float4(xx.x + g, xx.y + g, xx.z + g, xx.w + g);
    }
}

__global__ __launch_bounds__(THREADS)
void row_fused_generic_kernel(const float* __restrict__ x, const float* __restrict__ c,
                              const float* __restrict__ cb, const int* __restrict__ of_ptr,
                              float* __restrict__ out, int N) {
    const size_t base = (size_t)blockIdx.x * N;
    float partial = 0.f;
    for (int i = threadIdx.x; i < N; i += THREADS) partial += x[base + i] * c[i];
    #pragma unroll
    for (int off = 32; off > 0; off >>= 1) partial += __shfl_down(partial, off, 64);
    __shared__ float lds[THREADS / 64];
    if ((threadIdx.x & 63) == 0) lds[threadIdx.x >> 6] = partial;
    __syncthreads();
    float rs = *cb;
    #pragma unroll
    for (int w = 0; w < THREADS / 64; ++w) rs += lds[w];
    const float g = gelu_fast(rs / (float)(*of_ptr));
    for (int i = threadIdx.x; i < N; i += THREADS) out[base + i] = x[base + i] + g;
}

extern "C" void kernel_launch(void* const* d_in, const int* in_sizes, int n_in,
                              void* d_out, int out_size, void* d_ws, size_t ws_size,
                              hipStream_t stream) {
    const float* x    = (const float*)d_in[0];
    const float* W    = (const float*)d_in[1];
    const float* bias = (const float*)d_in[2];
    const float* sub  = (const float*)d_in[3];
    const int* of_ptr = (const int*)d_in[4];

    const int O = in_sizes[2];                       // 16384
    const int N = (int)((long long)in_sizes[1] / O); // 4096
    const int M = (int)((long long)in_sizes[0] / N); // 16384

    float* ws = (float*)d_ws;
    float* c  = ws;                    // N floats
    float* cb = ws + N;                // 1 float (padded to 64)
    float* g  = ws + N + 64;           // M floats
    float* partials = ws + N + 64 + M;

    const int colblocks = (N + THREADS * 4 - 1) / (THREADS * 4); // 4 for N=4096

    int chunks = CHUNKS;
    {
        long long maxChunks = ((long long)(ws_size / sizeof(float)) - N - 64 - M) / N;
        while (chunks > maxChunks && chunks > 8) chunks >>= 1;
    }
    const int rows_per_chunk = (O + chunks - 1) / chunks;

    dim3 g1(colblocks, chunks);
    colsum_partials_kernel<<<g1, THREADS, 0, stream>>>(W, partials, O, N, rows_per_chunk);

    reduce_par_kernel<<<(N >> 2) + 1, THREADS, 0, stream>>>(
        partials, bias, sub, c, cb, N, O, chunks);

    const int waves_per_block = THREADS / 64;
    const int G = (M + waves_per_block - 1) / waves_per_block;

    // shift s.t. float4-index -> row: N/4 elements per row (power of two)
    int shift = 0; { int q = N >> 2; while ((1 << shift) < q) ++shift; }
    const bool pow2 = ((N & (N - 1)) == 0);

    if (N == 4096) {
        rowsum_gelu_kernel<16><<<G, THREADS, 0, stream>>>(x, c, cb, of_ptr, g, M, N);
        const long long n4 = ((long long)M * N) >> 2;
        addg_kernel<<<2048, THREADS, 0, stream>>>(x, g, (float*)d_out, n4, shift);
    } else if (N == 2048 && pow2) {
        row_wave_kernel<8><<<G, THREADS, 0, stream>>>(x, c, cb, of_ptr, (float*)d_out, M, N);
    } else if (N == 8192 && pow2) {
        row_wave_kernel<32><<<G, THREADS, 0, stream>>>(x, c, cb, of_ptr, (float*)d_out, M, N);
    } else {
        row_fused_generic_kernel<<<M, THREADS, 0, stream>>>(x, c, cb, of_ptr, (float*)d_out, N);
    }
}

// Round 13
// 162.346 us; speedup vs baseline: 1.2496x; 1.2496x over previous
//
#include <hip/hip_runtime.h>
#include <math.h>

#define THREADS 256
#define CHUNKS 512          // stage-1 row chunks -> 4*512 = 2048 blocks (8/CU)

typedef int v4i __attribute__((ext_vector_type(4)));

__device__ __forceinline__ float4 ntload4(const float* p) {
    v4i t = __builtin_nontemporal_load(reinterpret_cast<const v4i*>(p));
    float4 r;
    r.x = __int_as_float(t.x); r.y = __int_as_float(t.y);
    r.z = __int_as_float(t.z); r.w = __int_as_float(t.w);
    return r;
}
__device__ __forceinline__ void ntstore4(float* p, const float4 v) {
    v4i t;
    t.x = __float_as_int(v.x); t.y = __float_as_int(v.y);
    t.z = __float_as_int(v.z); t.w = __float_as_int(v.w);
    __builtin_nontemporal_store(t, reinterpret_cast<v4i*>(p));
}

// gelu_tanh(m) = 0.5*m*(1+tanh(inner)) = m * sigmoid(2*inner)
__device__ __forceinline__ float gelu_fast(float m) {
    const float inner = 0.7978845608028654f * (m + 0.044715f * m * m * m);
    return m / (1.0f + __expf(-2.0f * inner));
}

// ---------------- Kernel 1: column partial sums of W (deterministic) -------
__global__ __launch_bounds__(THREADS)
void colsum_partials_kernel(const float* __restrict__ W, float* __restrict__ partials,
                            int O, int N, int rows_per_chunk) {
    int col = (blockIdx.x * THREADS + threadIdx.x) * 4;
    if (col >= N) return;
    int r0 = blockIdx.y * rows_per_chunk;
    int r1 = r0 + rows_per_chunk; if (r1 > O) r1 = O;
    float ax = 0.f, ay = 0.f, az = 0.f, aw = 0.f;
    #pragma unroll 4
    for (int r = r0; r < r1; ++r) {
        const float4 v = ntload4(W + (size_t)r * N + col);   // W streamed once
        ax += v.x; ay += v.y; az += v.z; aw += v.w;
    }
    // regular store: keep partials cache-resident for the reduce
    *reinterpret_cast<float4*>(partials + (size_t)blockIdx.y * N + col) =
        make_float4(ax, ay, az, aw);
}

// ------ Kernel 2: PARALLEL reduce partials -> c (1024 blocks) + bias sum ----
__global__ __launch_bounds__(THREADS)
void reduce_par_kernel(const float* __restrict__ partials,
                       const float* __restrict__ bias, const float* __restrict__ sub,
                       float* __restrict__ c, float* __restrict__ cb,
                       int N, int O, int chunks) {
    const int ncolg = N >> 2;
    const int t = threadIdx.x;
    if ((int)blockIdx.x == ncolg) {          // bias block
        float s = 0.f;
        for (int i = t; i < O; i += THREADS) s += bias[i] - sub[i];
        #pragma unroll
        for (int off = 32; off > 0; off >>= 1) s += __shfl_down(s, off, 64);
        __shared__ float lds[THREADS / 64];
        if ((t & 63) == 0) lds[t >> 6] = s;
        __syncthreads();
        if (t == 0) {
            float tt = 0.f;
            #pragma unroll
            for (int w = 0; w < THREADS / 64; ++w) tt += lds[w];
            *cb = tt;
        }
        return;
    }
    const int colg = blockIdx.x << 2;
    float ax = 0.f, ay = 0.f, az = 0.f, aw = 0.f;
    for (int k = t; k < chunks; k += THREADS) {
        const float4 v = *reinterpret_cast<const float4*>(partials + (size_t)k * N + colg);
        ax += v.x; ay += v.y; az += v.z; aw += v.w;
    }
    #pragma unroll
    for (int off = 32; off > 0; off >>= 1) {
        ax += __shfl_down(ax, off, 64);
        ay += __shfl_down(ay, off, 64);
        az += __shfl_down(az, off, 64);
        aw += __shfl_down(aw, off, 64);
    }
    __shared__ float4 lds4[THREADS / 64];
    if ((t & 63) == 0) lds4[t >> 6] = make_float4(ax, ay, az, aw);
    __syncthreads();
    if (t == 0) {
        float4 r = lds4[0];
        #pragma unroll
        for (int w = 1; w < THREADS / 64; ++w) {
            r.x += lds4[w].x; r.y += lds4[w].y; r.z += lds4[w].z; r.w += lds4[w].w;
        }
        *reinterpret_cast<float4*>(c + colg) = r;
    }
}

// ------------- Kernel 3: WAVE-per-row fused dot->gelu->residual --------------
// 64 lanes own one row: no barriers, no LDS, fully independent waves.
template<int VPL>
__global__ __launch_bounds__(THREADS)
void row_wave_kernel(const float* __restrict__ x, const float* __restrict__ c,
                     const float* __restrict__ cb, const int* __restrict__ of_ptr,
                     float* __restrict__ out, int M, int N) {
    const int wave = threadIdx.x >> 6;
    const int lane = threadIdx.x & 63;
    const int row = blockIdx.x * (THREADS / 64) + wave;
    if (row >= M) return;
    const size_t base = (size_t)row * N;

    float4 xv[VPL];
    float partial = 0.f;
    #pragma unroll
    for (int k = 0; k < VPL; ++k) {
        const int idx = (k * 64 + lane) * 4;
        const float4 xx = ntload4(x + base + idx);                    // streamed once
        const float4 cc = *reinterpret_cast<const float4*>(c + idx);  // cache-resident
        xv[k] = xx;
        partial += xx.x * cc.x + xx.y * cc.y + xx.z * cc.z + xx.w * cc.w;
    }

    #pragma unroll
    for (int off = 1; off < 64; off <<= 1) partial += __shfl_xor(partial, off, 64);

    const float g = gelu_fast((partial + *cb) / (float)(*of_ptr));

    #pragma unroll
    for (int k = 0; k < VPL; ++k) {
        const int idx = (k * 64 + lane) * 4;
        const float4 xx = xv[k];
        ntstore4(out + base + idx, make_float4(xx.x + g, xx.y + g, xx.z + g, xx.w + g));
    }
}

// generic fallback for unexpected N (block-per-row, one barrier)
__global__ __launch_bounds__(THREADS)
void row_fused_generic_kernel(const float* __restrict__ x, const float* __restrict__ c,
                              const float* __restrict__ cb, const int* __restrict__ of_ptr,
                              float* __restrict__ out, int N) {
    const size_t base = (size_t)blockIdx.x * N;
    float partial = 0.f;
    for (int i = threadIdx.x; i < N; i += THREADS) partial += x[base + i] * c[i];
    #pragma unroll
    for (int off = 32; off > 0; off >>= 1) partial += __shfl_down(partial, off, 64);
    __shared__ float lds[THREADS / 64];
    if ((threadIdx.x & 63) == 0) lds[threadIdx.x >> 6] = partial;
    __syncthreads();
    float rs = *cb;
    #pragma unroll
    for (int w = 0; w < THREADS / 64; ++w) rs += lds[w];
    const float g = gelu_fast(rs / (float)(*of_ptr));
    for (int i = threadIdx.x; i < N; i += THREADS) out[base + i] = x[base + i] + g;
}

extern "C" void kernel_launch(void* const* d_in, const int* in_sizes, int n_in,
                              void* d_out, int out_size, void* d_ws, size_t ws_size,
                              hipStream_t stream) {
    const float* x    = (const float*)d_in[0];
    const float* W    = (const float*)d_in[1];
    const float* bias = (const float*)d_in[2];
    const float* sub  = (const float*)d_in[3];
    const int* of_ptr = (const int*)d_in[4];

    const int O = in_sizes[2];                       // 16384
    const int N = (int)((long long)in_sizes[1] / O); // 4096
    const int M = (int)((long long)in_sizes[0] / N); // 16384

    float* ws = (float*)d_ws;
    float* c  = ws;            // N floats
    float* cb = ws + N;        // 1 float (padded to 64)
    float* partials = ws + N + 64;

    const int colblocks = (N + THREADS * 4 - 1) / (THREADS * 4); // 4 for N=4096

    int chunks = CHUNKS;
    {
        long long maxChunks = ((long long)(ws_size / sizeof(float)) - N - 64) / N;
        while (chunks > maxChunks && chunks > 8) chunks >>= 1;
    }
    const int rows_per_chunk = (O + chunks - 1) / chunks;

    dim3 g1(colblocks, chunks);
    colsum_partials_kernel<<<g1, THREADS, 0, stream>>>(W, partials, O, N, rows_per_chunk);

    reduce_par_kernel<<<(N >> 2) + 1, THREADS, 0, stream>>>(
        partials, bias, sub, c, cb, N, O, chunks);

    const int waves_per_block = THREADS / 64;
    const int G = (M + waves_per_block - 1) / waves_per_block;
    if (N == 4096) {
        row_wave_kernel<16><<<G, THREADS, 0, stream>>>(x, c, cb, of_ptr, (float*)d_out, M, N);
    } else if (N == 2048) {
        row_wave_kernel<8><<<G, THREADS, 0, stream>>>(x, c, cb, of_ptr, (float*)d_out, M, N);
    } else if (N == 8192) {
        row_wave_kernel<32><<<G, THREADS, 0, stream>>>(x, c, cb, of_ptr, (float*)d_out, M, N);
    } else {
        row_fused_generic_kernel<<<M, THREADS, 0, stream>>>(x, c, cb, of_ptr, (float*)d_out, N);
    }
}

// Round 14
// 161.662 us; speedup vs baseline: 1.2549x; 1.0042x over previous
//
#include <hip/hip_runtime.h>
#include <math.h>

#define THREADS 256
#define CHUNKS 512          // stage-1 row chunks -> 4*512 = 2048 blocks (8/CU)

typedef int v4i __attribute__((ext_vector_type(4)));

__device__ __forceinline__ float4 ntload4(const float* p) {
    v4i t = __builtin_nontemporal_load(reinterpret_cast<const v4i*>(p));
    float4 r;
    r.x = __int_as_float(t.x); r.y = __int_as_float(t.y);
    r.z = __int_as_float(t.z); r.w = __int_as_float(t.w);
    return r;
}
__device__ __forceinline__ void ntstore4(float* p, const float4 v) {
    v4i t;
    t.x = __float_as_int(v.x); t.y = __float_as_int(v.y);
    t.z = __float_as_int(v.z); t.w = __float_as_int(v.w);
    __builtin_nontemporal_store(t, reinterpret_cast<v4i*>(p));
}

// gelu_tanh(m) = 0.5*m*(1+tanh(inner)) = m * sigmoid(2*inner)
__device__ __forceinline__ float gelu_fast(float m) {
    const float inner = 0.7978845608028654f * (m + 0.044715f * m * m * m);
    return m / (1.0f + __expf(-2.0f * inner));
}

// ---------------- Kernel 1: column partial sums of W (deterministic) -------
__global__ __launch_bounds__(THREADS)
void colsum_partials_kernel(const float* __restrict__ W, float* __restrict__ partials,
                            int O, int N, int rows_per_chunk) {
    int col = (blockIdx.x * THREADS + threadIdx.x) * 4;
    if (col >= N) return;
    int r0 = blockIdx.y * rows_per_chunk;
    int r1 = r0 + rows_per_chunk; if (r1 > O) r1 = O;
    float ax = 0.f, ay = 0.f, az = 0.f, aw = 0.f;
    #pragma unroll 4
    for (int r = r0; r < r1; ++r) {
        const float4 v = ntload4(W + (size_t)r * N + col);   // W streamed once
        ax += v.x; ay += v.y; az += v.z; aw += v.w;
    }
    // regular store: keep partials cache-resident for the reduce
    *reinterpret_cast<float4*>(partials + (size_t)blockIdx.y * N + col) =
        make_float4(ax, ay, az, aw);
}

// ------ Kernel 2: PARALLEL reduce partials -> c (1024 blocks) + bias sum ----
__global__ __launch_bounds__(THREADS)
void reduce_par_kernel(const float* __restrict__ partials,
                       const float* __restrict__ bias, const float* __restrict__ sub,
                       float* __restrict__ c, float* __restrict__ cb,
                       int N, int O, int chunks) {
    const int ncolg = N >> 2;
    const int t = threadIdx.x;
    if ((int)blockIdx.x == ncolg) {          // bias block
        float s = 0.f;
        for (int i = t; i < O; i += THREADS) s += bias[i] - sub[i];
        #pragma unroll
        for (int off = 32; off > 0; off >>= 1) s += __shfl_down(s, off, 64);
        __shared__ float lds[THREADS / 64];
        if ((t & 63) == 0) lds[t >> 6] = s;
        __syncthreads();
        if (t == 0) {
            float tt = 0.f;
            #pragma unroll
            for (int w = 0; w < THREADS / 64; ++w) tt += lds[w];
            *cb = tt;
        }
        return;
    }
    const int colg = blockIdx.x << 2;
    float ax = 0.f, ay = 0.f, az = 0.f, aw = 0.f;
    for (int k = t; k < chunks; k += THREADS) {
        const float4 v = *reinterpret_cast<const float4*>(partials + (size_t)k * N + colg);
        ax += v.x; ay += v.y; az += v.z; aw += v.w;
    }
    #pragma unroll
    for (int off = 32; off > 0; off >>= 1) {
        ax += __shfl_down(ax, off, 64);
        ay += __shfl_down(ay, off, 64);
        az += __shfl_down(az, off, 64);
        aw += __shfl_down(aw, off, 64);
    }
    __shared__ float4 lds4[THREADS / 64];
    if ((t & 63) == 0) lds4[t >> 6] = make_float4(ax, ay, az, aw);
    __syncthreads();
    if (t == 0) {
        float4 r = lds4[0];
        #pragma unroll
        for (int w = 1; w < THREADS / 64; ++w) {
            r.x += lds4[w].x; r.y += lds4[w].y; r.z += lds4[w].z; r.w += lds4[w].w;
        }
        *reinterpret_cast<float4*>(c + colg) = r;
    }
}

// ------------- Kernel 3: WAVE-per-row fused dot->gelu->residual --------------
// __launch_bounds__(256, 2): raise VGPR cap to ~256 so xv[VPL] stays RESIDENT
// (R9 profile showed VGPR_Count=64 -> compiler rematerialized x loads -> x
// was fetched TWICE from HBM. Keeping the row in registers reads x once.)
template<int VPL>
__global__ __launch_bounds__(THREADS, 2)
void row_wave_kernel(const float* __restrict__ x, const float* __restrict__ c,
                     const float* __restrict__ cb, const int* __restrict__ of_ptr,
                     float* __restrict__ out, int M, int N) {
    const int wave = threadIdx.x >> 6;
    const int lane = threadIdx.x & 63;
    const int row = blockIdx.x * (THREADS / 64) + wave;
    if (row >= M) return;
    const size_t base = (size_t)row * N;

    float4 xv[VPL];
    float partial = 0.f;
    #pragma unroll
    for (int k = 0; k < VPL; ++k) {
        const int idx = (k * 64 + lane) * 4;
        const float4 xx = ntload4(x + base + idx);                    // streamed once
        const float4 cc = *reinterpret_cast<const float4*>(c + idx);  // cache-resident
        xv[k] = xx;
        partial += xx.x * cc.x + xx.y * cc.y + xx.z * cc.z + xx.w * cc.w;
    }

    #pragma unroll
    for (int off = 1; off < 64; off <<= 1) partial += __shfl_xor(partial, off, 64);

    const float g = gelu_fast((partial + *cb) / (float)(*of_ptr));

    #pragma unroll
    for (int k = 0; k < VPL; ++k) {
        const int idx = (k * 64 + lane) * 4;
        const float4 xx = xv[k];
        ntstore4(out + base + idx, make_float4(xx.x + g, xx.y + g, xx.z + g, xx.w + g));
    }
}

// generic fallback for unexpected N (block-per-row, one barrier)
__global__ __launch_bounds__(THREADS)
void row_fused_generic_kernel(const float* __restrict__ x, const float* __restrict__ c,
                              const float* __restrict__ cb, const int* __restrict__ of_ptr,
                              float* __restrict__ out, int N) {
    const size_t base = (size_t)blockIdx.x * N;
    float partial = 0.f;
    for (int i = threadIdx.x; i < N; i += THREADS) partial += x[base + i] * c[i];
    #pragma unroll
    for (int off = 32; off > 0; off >>= 1) partial += __shfl_down(partial, off, 64);
    __shared__ float lds[THREADS / 64];
    if ((threadIdx.x & 63) == 0) lds[threadIdx.x >> 6] = partial;
    __syncthreads();
    float rs = *cb;
    #pragma unroll
    for (int w = 0; w < THREADS / 64; ++w) rs += lds[w];
    const float g = gelu_fast(rs / (float)(*of_ptr));
    for (int i = threadIdx.x; i < N; i += THREADS) out[base + i] = x[base + i] + g;
}

extern "C" void kernel_launch(void* const* d_in, const int* in_sizes, int n_in,
                              void* d_out, int out_size, void* d_ws, size_t ws_size,
                              hipStream_t stream) {
    const float* x    = (const float*)d_in[0];
    const float* W    = (const float*)d_in[1];
    const float* bias = (const float*)d_in[2];
    const float* sub  = (const float*)d_in[3];
    const int* of_ptr = (const int*)d_in[4];

    const int O = in_sizes[2];                       // 16384
    const int N = (int)((long long)in_sizes[1] / O); // 4096
    const int M = (int)((long long)in_sizes[0] / N); // 16384

    float* ws = (float*)d_ws;
    float* c  = ws;            // N floats
    float* cb = ws + N;        // 1 float (padded to 64)
    float* partials = ws + N + 64;

    const int colblocks = (N + THREADS * 4 - 1) / (THREADS * 4); // 4 for N=4096

    int chunks = CHUNKS;
    {
        long long maxChunks = ((long long)(ws_size / sizeof(float)) - N - 64) / N;
        while (chunks > maxChunks && chunks > 8) chunks >>= 1;
    }
    const int rows_per_chunk = (O + chunks - 1) / chunks;

    dim3 g1(colblocks, chunks);
    colsum_partials_kernel<<<g1, THREADS, 0, stream>>>(W, partials, O, N, rows_per_chunk);

    reduce_par_kernel<<<(N >> 2) + 1, THREADS, 0, stream>>>(
        partials, bias, sub, c, cb, N, O, chunks);

    const int waves_per_block = THREADS / 64;
    const int G = (M + waves_per_block - 1) / waves_per_block;
    if (N == 4096) {
        row_wave_kernel<16><<<G, THREADS, 0, stream>>>(x, c, cb, of_ptr, (float*)d_out, M, N);
    } else if (N == 2048) {
        row_wave_kernel<8><<<G, THREADS, 0, stream>>>(x, c, cb, of_ptr, (float*)d_out, M, N);
    } else if (N == 8192) {
        row_wave_kernel<32><<<G, THREADS, 0, stream>>>(x, c, cb, of_ptr, (float*)d_out, M, N);
    } else {
        row_fused_generic_kernel<<<M, THREADS, 0, stream>>>(x, c, cb, of_ptr, (float*)d_out, N);
    }
}